// Round 8
// baseline (215.770 us; speedup 1.0000x reference)
//
#include <hip/hip_runtime.h>
#include <hip/hip_bf16.h>
#include <hip/hip_fp16.h>
#include <stdint.h>

// Problem dims (fixed): N=64, C=192, T=64, V=25, H=6, d=32, B=N*V=1600
#define N_ 64
#define C_ 192
#define T_ 64
#define V_ 25
#define H_ 6
#define D_ 32
#define B_ 1600
#define NQ_ (3 * C_ * C_)   // 110592
#define NO_ (C_ * C_)       // 36864

typedef __attribute__((ext_vector_type(8))) short s16x8;
typedef __attribute__((ext_vector_type(4))) float f32x4;

__device__ __forceinline__ unsigned short f2bf(float f) {
    union { float f; uint32_t u; } v; v.f = f;
    uint32_t r = v.u + 0x7FFFu + ((v.u >> 16) & 1u);   // RNE
    return (unsigned short)(r >> 16);
}

// ---------------------------------------------------------------------------
// Kernel 0: weights + rel_emb -> bf16 (relb padded to 128 rows, row127 = 0)
// ---------------------------------------------------------------------------
__global__ __launch_bounds__(256) void k_wconv(const float* __restrict__ wq,
                                               const float* __restrict__ wo,
                                               const float* __restrict__ rel_emb,
                                               unsigned short* __restrict__ wqb,
                                               unsigned short* __restrict__ wob,
                                               unsigned short* __restrict__ relb) {
    int i = blockIdx.x * 256 + threadIdx.x;
    if (i < NQ_) wqb[i] = f2bf(wq[i]);
    else if (i < NQ_ + NO_) wob[i - NQ_] = f2bf(wo[i - NQ_]);
    else {
        int j = i - (NQ_ + NO_);
        if (j < 128 * 32) {
            int m = j >> 5;
            relb[j] = (m < 127) ? f2bf(rel_emb[j]) : (unsigned short)0;
        }
    }
}

// ---------------------------------------------------------------------------
// Kernel 1: x (N,C,T,V) fp32 -> xt[(n*V+v)][t][c] bf16
// ---------------------------------------------------------------------------
__global__ __launch_bounds__(256) void k_xpose(const float* __restrict__ x,
                                               unsigned short* __restrict__ xt) {
    int bid = blockIdx.x;
    int n = bid / 12, r = bid % 12, cg = r >> 1, ih = r & 1;
    __shared__ unsigned short tile[800][40];   // 64000 B
    int tid = threadIdx.x;
    {
        int cc = tid >> 3, part = tid & 7;     // cc 0..31, 100 elems each
        const float4* src = (const float4*)(x + ((size_t)n * C_ + cg * 32 + cc) * 1600
                                              + ih * 800 + part * 100);
#pragma unroll
        for (int u = 0; u < 25; ++u) {
            float4 f = src[u];
            int i = part * 100 + u * 4;
            tile[i + 0][cc] = f2bf(f.x);
            tile[i + 1][cc] = f2bf(f.y);
            tile[i + 2][cc] = f2bf(f.z);
            tile[i + 3][cc] = f2bf(f.w);
        }
    }
    __syncthreads();
    for (int i = tid; i < 800; i += 256) {
        int gi = ih * 800 + i;
        int t = (gi * 5243) >> 17;             // gi/25 (exact for gi<1600)
        int v = gi - t * 25;
        unsigned short* dst = xt + (((size_t)(n * V_ + v) * T_) + t) * C_ + cg * 32;
        const s16x8* srow = (const s16x8*)&tile[i][0];
        ((s16x8*)dst)[0] = srow[0];
        ((s16x8*)dst)[1] = srow[1];
        ((s16x8*)dst)[2] = srow[2];
        ((s16x8*)dst)[3] = srow[3];
    }
}

// ---------------------------------------------------------------------------
// Kernel 2: QKV flat GEMM W(576x192) @ xt^T(192x102400), tile 64x256.
// All 24 B-fragments HOISTED into registers before W staging (latency hidden
// under stage+barrier); 96 MFMAs back-to-back.  Epilogue:
//   mo 0..5 (q,k): column-major LDS bounce -> qT/kT[b][t][192] (128B chunks)
//   mo 6..8 (v)  : row-major bounce -> vB[b][d][t] (coalesced rows)
// ---------------------------------------------------------------------------
__global__ __launch_bounds__(256) void k_qkv_flat(const unsigned short* __restrict__ Wb,
                                                  const float* __restrict__ bias,
                                                  const unsigned short* __restrict__ xt,
                                                  unsigned short* __restrict__ qT,
                                                  unsigned short* __restrict__ kT,
                                                  unsigned short* __restrict__ vB) {
    int virt = (blockIdx.x & 7) * 450 + (blockIdx.x >> 3);   // 3600 = 8*450
    int nt0 = virt / 9, mo = virt - nt0 * 9;                 // nt-major
    int n0 = nt0 * 256;

    __shared__ __align__(16) unsigned short U[20480];   // 40.96 KB union
    // A-view: U[row*200+k] (64x192)  qk-bounce: U[col*80+o]  v-bounce: U[row*264+col]

    int tid = threadIdx.x;
    int wave = tid >> 6, lane = tid & 63;
    int lr = lane & 15, lg = lane >> 4;
    int nbase = n0 + wave * 64;

    // hoist ALL B-frags (24 global 16B loads in flight)
    s16x8 bfr[6][4];
#pragma unroll
    for (int kk = 0; kk < 6; ++kk)
#pragma unroll
        for (int nt = 0; nt < 4; ++nt)
            bfr[kk][nt] = *(const s16x8*)(xt +
                (size_t)(nbase + nt * 16 + lr) * C_ + kk * 32 + lg * 8);

    // stage W tile (latency of bfr loads hides under this + barrier)
    for (int ci = tid; ci < 64 * 24; ci += 256) {
        int row = ci / 24, seg = ci - (ci / 24) * 24;
        *(s16x8*)&U[row * 200 + seg * 8] =
            *(const s16x8*)(Wb + (size_t)(mo * 64 + row) * C_ + seg * 8);
    }
    __syncthreads();

    f32x4 acc[4][4];
#pragma unroll
    for (int mt = 0; mt < 4; ++mt)
#pragma unroll
        for (int nt = 0; nt < 4; ++nt) acc[mt][nt] = (f32x4){0.f, 0.f, 0.f, 0.f};

#pragma unroll
    for (int kk = 0; kk < 6; ++kk) {
        s16x8 afr[4];
#pragma unroll
        for (int mt = 0; mt < 4; ++mt)
            afr[mt] = *(const s16x8*)&U[(mt * 16 + lr) * 200 + kk * 32 + lg * 8];
#pragma unroll
        for (int mt = 0; mt < 4; ++mt)
#pragma unroll
            for (int nt = 0; nt < 4; ++nt)
                acc[mt][nt] = __builtin_amdgcn_mfma_f32_16x16x32_bf16(afr[mt], bfr[kk][nt], acc[mt][nt], 0, 0, 0);
    }
    __syncthreads();                            // done reading A-view

    int b0 = nt0 * 4;
    if (mo < 6) {
        // q/k: column-major bounce U[col*80 + o]
#pragma unroll
        for (int mt = 0; mt < 4; ++mt)
#pragma unroll
            for (int nt = 0; nt < 4; ++nt)
#pragma unroll
                for (int r2 = 0; r2 < 4; ++r2) {
                    int o = mt * 16 + lg * 4 + r2;
                    int col = wave * 64 + nt * 16 + lr;
                    U[col * 80 + o] = f2bf(acc[mt][nt][r2] + bias[mo * 64 + o]);
                }
        __syncthreads();
        unsigned short* dst0 = (mo < 3 ? qT : kT);
        int o0 = (mo % 3) * 64;
        for (int ci = tid; ci < 2048; ci += 256) {
            int col = ci >> 3, seg = ci & 7;
            int g = n0 + col;
            int bb = g >> 6, tt = g & 63;
            *(s16x8*)(dst0 + ((size_t)bb * T_ + tt) * C_ + o0 + seg * 8) =
                *(const s16x8*)&U[col * 80 + seg * 8];
        }
    } else {
        // v: row-major bounce U[row*264 + col]
#pragma unroll
        for (int mt = 0; mt < 4; ++mt)
#pragma unroll
            for (int nt = 0; nt < 4; ++nt)
#pragma unroll
                for (int r2 = 0; r2 < 4; ++r2) {
                    int o = mt * 16 + lg * 4 + r2;
                    U[o * 264 + wave * 64 + nt * 16 + lr] =
                        f2bf(acc[mt][nt][r2] + bias[mo * 64 + o]);
                }
        __syncthreads();
        int d0 = (mo - 6) * 64;
        for (int ci = tid; ci < 2048; ci += 256) {
            int row = ci >> 5, cc = ci & 31;
            int bl = cc >> 3, t8 = (cc & 7) * 8;
            *(s16x8*)(vB + ((size_t)(b0 + bl) * C_ + d0 + row) * T_ + t8) =
                *(const s16x8*)&U[row * 264 + cc * 8];
        }
    }
}

// ---------------------------------------------------------------------------
// Kernel 3: fused attention per (b,h).  Row-copy staging (vectorized,
// conflict-light) from qT/kT[b][t][192] and vB[b][d][t]; no swizzle VALU.
// ---------------------------------------------------------------------------
__global__ __launch_bounds__(256) void k_attn(const unsigned short* __restrict__ qT,
                                              const unsigned short* __restrict__ kT,
                                              const unsigned short* __restrict__ vB,
                                              const unsigned short* __restrict__ relb,
                                              unsigned short* __restrict__ aT) {
    int virt = (blockIdx.x & 7) * (B_ * H_ / 8) + (blockIdx.x >> 3);
    int b = virt / H_, h = virt % H_;
    __shared__ unsigned short qt[64][40];      // [t][d]
    __shared__ unsigned short kt[64][40];      // [s][d]
    __shared__ unsigned short vsm[32][88];     // [d][t]
    __shared__ unsigned short rel[128][40];    // [m][d], row127 = 0
    __shared__ unsigned short wls[64][72];     // softmax weights [t][s]
    __shared__ __half rel_l[64][132];          // rel_logits [t][m]; ao aliased
    unsigned short (*ao)[40] = (unsigned short(*)[40])&rel_l[0][0];

    int tid = threadIdx.x;
    {
        int t = tid >> 2, sg = tid & 3;
        *(s16x8*)&qt[t][sg * 8] =
            *(const s16x8*)(qT + ((size_t)b * T_ + t) * C_ + h * D_ + sg * 8);
        *(s16x8*)&kt[t][sg * 8] =
            *(const s16x8*)(kT + ((size_t)b * T_ + t) * C_ + h * D_ + sg * 8);
    }
    {
        int d = tid >> 3, tg = tid & 7;
        *(s16x8*)&vsm[d][tg * 8] =
            *(const s16x8*)(vB + ((size_t)b * C_ + h * D_ + d) * T_ + tg * 8);
    }
    {
        int m = tid >> 1, hf = tid & 1;
        s16x8* dst = (s16x8*)&rel[m][hf * 16];
        const s16x8* src = (const s16x8*)(relb + m * 32 + hf * 16);
        dst[0] = src[0];
        dst[1] = src[1];
    }
    __syncthreads();

    int wave = tid >> 6, lane = tid & 63;
    int lr = lane & 15, lg = lane >> 4;
    int t0 = wave * 16;
    int tA = t0 + lr;
    s16x8 afq = *(const s16x8*)&qt[tA][lg * 8];

    // QK^T: 4 N-tiles over s
    f32x4 accS[4];
#pragma unroll
    for (int nt = 0; nt < 4; ++nt) {
        s16x8 bf = *(const s16x8*)&kt[nt * 16 + lr][lg * 8];
        f32x4 z = (f32x4){0.f, 0.f, 0.f, 0.f};
        accS[nt] = __builtin_amdgcn_mfma_f32_16x16x32_bf16(afq, bf, z, 0, 0, 0);
    }
    // rel logits: 8 N-tiles over m -> rel_l (fp16)
#pragma unroll
    for (int mt = 0; mt < 8; ++mt) {
        int m = mt * 16 + lr;
        s16x8 bf = *(const s16x8*)&rel[m][lg * 8];
        f32x4 z = (f32x4){0.f, 0.f, 0.f, 0.f};
        f32x4 rr = __builtin_amdgcn_mfma_f32_16x16x32_bf16(afq, bf, z, 0, 0, 0);
#pragma unroll
        for (int r2 = 0; r2 < 4; ++r2)
            rel_l[t0 + lg * 4 + r2][mt * 16 + lr] = __float2half(rr[r2]);
    }
    __syncthreads();

    // softmax (fp32): lane owns 4 rows (t0+lg*4+r2) x 4 cols (nt*16+lr)
    float vals[4][4], mx[4], inv[4];
#pragma unroll
    for (int r2 = 0; r2 < 4; ++r2) {
        int t = t0 + lg * 4 + r2;
        float m0 = -1e30f;
#pragma unroll
        for (int nt = 0; nt < 4; ++nt) {
            int s = nt * 16 + lr;
            float v = accS[nt][r2] + __half2float(rel_l[t][s - t + 63]);
            vals[nt][r2] = v;
            m0 = fmaxf(m0, v);
        }
        m0 = fmaxf(m0, __shfl_xor(m0, 1));
        m0 = fmaxf(m0, __shfl_xor(m0, 2));
        m0 = fmaxf(m0, __shfl_xor(m0, 4));
        m0 = fmaxf(m0, __shfl_xor(m0, 8));
        mx[r2] = m0;
    }
#pragma unroll
    for (int r2 = 0; r2 < 4; ++r2) {
        float s0 = 0.f;
#pragma unroll
        for (int nt = 0; nt < 4; ++nt) {
            float e = __expf(vals[nt][r2] - mx[r2]);
            vals[nt][r2] = e;
            s0 += e;
        }
        s0 += __shfl_xor(s0, 1);
        s0 += __shfl_xor(s0, 2);
        s0 += __shfl_xor(s0, 4);
        s0 += __shfl_xor(s0, 8);
        inv[r2] = 1.0f / s0;
    }
#pragma unroll
    for (int r2 = 0; r2 < 4; ++r2) {
        int t = t0 + lg * 4 + r2;
#pragma unroll
        for (int nt = 0; nt < 4; ++nt)
            wls[t][nt * 16 + lr] = f2bf(vals[nt][r2] * inv[r2]);
    }
    __syncthreads();   // wls ready; also fences rel_l reads before ao overwrite

    // PV: attn[t][dd] = sum_s w[t][s] * v[dd][s]
    f32x4 accO[2];
    accO[0] = (f32x4){0.f, 0.f, 0.f, 0.f};
    accO[1] = (f32x4){0.f, 0.f, 0.f, 0.f};
#pragma unroll
    for (int ks = 0; ks < 2; ++ks) {
        s16x8 pa = *(const s16x8*)&wls[tA][ks * 32 + lg * 8];
#pragma unroll
        for (int nt = 0; nt < 2; ++nt) {
            s16x8 bf = *(const s16x8*)&vsm[nt * 16 + lr][ks * 32 + lg * 8];
            accO[nt] = __builtin_amdgcn_mfma_f32_16x16x32_bf16(pa, bf, accO[nt], 0, 0, 0);
        }
    }
#pragma unroll
    for (int nt = 0; nt < 2; ++nt)
#pragma unroll
        for (int r2 = 0; r2 < 4; ++r2)
            ao[t0 + lg * 4 + r2][nt * 16 + lr] = f2bf(accO[nt][r2]);
    __syncthreads();

    // scrambled write: aT[b][tout][h*32+qr] = ao[tA][dA]
    unsigned short* dstb = aT + (size_t)b * T_ * C_ + h * D_;
#pragma unroll
    for (int it = 0; it < 8; ++it) {
        int idx = it * 256 + tid;
        int qr = idx & 31, tout = idx >> 5;
        int ii = tout & 31;
        int j = 2 * qr + (tout >> 5);
        int tAo = 2 * ii + (j >> 5);
        int dA = j & 31;
        dstb[(size_t)tout * C_ + qr] = ao[tAo][dA];
    }
}

// ---------------------------------------------------------------------------
// Kernel 4: out GEMM (bf16 MFMA), writes final (N,C,T,V) fp32. XCD-swizzled.
// ---------------------------------------------------------------------------
__global__ __launch_bounds__(256) void k_out(const unsigned short* __restrict__ Wb,
                                             const float* __restrict__ bias,
                                             const unsigned short* __restrict__ aT,
                                             float* __restrict__ out) {
    int virt = (blockIdx.x & 7) * (768 / 8) + (blockIdx.x >> 3);
    int n = virt / 12, r = virt % 12, mo = r >> 2, tc = r & 3;
    __shared__ unsigned short Bs[400][40];     // [col][k], 32KB
    int tid = threadIdx.x;
    int wave = tid >> 6, lane = tid & 63;
    int lr = lane & 15, lg = lane >> 4;

    f32x4 acc[25];
#pragma unroll
    for (int j = 0; j < 25; ++j) acc[j] = (f32x4){0.f, 0.f, 0.f, 0.f};

    const unsigned short* arow = Wb + (size_t)(mo * 64 + wave * 16 + lr) * C_ + lg * 8;

    for (int k0 = 0; k0 < C_; k0 += 32) {
        __syncthreads();
        for (int col = tid; col < 400; col += 256) {
            int tl = (col * 41) >> 10;         // col/25 (exact for col<624)
            int v = col - tl * 25;
            const s16x8* src = (const s16x8*)(aT +
                ((size_t)(n * V_ + v) * T_ + tc * 16 + tl) * C_ + k0);
            s16x8* dst = (s16x8*)&Bs[col][0];
            dst[0] = src[0]; dst[1] = src[1]; dst[2] = src[2]; dst[3] = src[3];
        }
        __syncthreads();
        s16x8 a = *(const s16x8*)(arow + k0);
#pragma unroll
        for (int j = 0; j < 25; ++j) {
            s16x8 bf = *(const s16x8*)&Bs[j * 16 + lr][lg * 8];
            acc[j] = __builtin_amdgcn_mfma_f32_16x16x32_bf16(a, bf, acc[j], 0, 0, 0);
        }
    }
#pragma unroll
    for (int j = 0; j < 25; ++j) {
        int c = j * 16 + lr;
        int tl = (c * 41) >> 10;
        int v = c - tl * 25;
        int t = tc * 16 + tl;
#pragma unroll
        for (int r2 = 0; r2 < 4; ++r2) {
            int o = mo * 64 + wave * 16 + lg * 4 + r2;
            out[(((size_t)n * C_ + o) * T_ + t) * V_ + v] = acc[j][r2] + bias[o];
        }
    }
}

// ---------------------------------------------------------------------------
extern "C" void kernel_launch(void* const* d_in, const int* in_sizes, int n_in,
                              void* d_out, int out_size, void* d_ws, size_t ws_size,
                              hipStream_t stream) {
    const float* x       = (const float*)d_in[0];
    const float* w_qkv   = (const float*)d_in[1];
    const float* b_qkv   = (const float*)d_in[2];
    const float* w_out   = (const float*)d_in[3];
    const float* b_out   = (const float*)d_in[4];
    const float* rel_emb = (const float*)d_in[5];
    float* out = (float*)d_out;

    // workspace (ushorts): xt | qT | kT | vB | aT | wqb | wob | relb (~197 MB)
    const size_t PLANE = (size_t)B_ * T_ * C_;   // 19,660,800
    unsigned short* xt   = (unsigned short*)d_ws;
    unsigned short* qTb  = xt + PLANE;
    unsigned short* kTb  = qTb + PLANE;
    unsigned short* vBb  = kTb + PLANE;
    unsigned short* aTb  = vBb + PLANE;
    unsigned short* wqb  = aTb + PLANE;
    unsigned short* wob  = wqb + (size_t)NQ_;
    unsigned short* relb = wob + (size_t)NO_;

    k_wconv<<<592, 256, 0, stream>>>(w_qkv, w_out, rel_emb, wqb, wob, relb);
    k_xpose<<<768, 256, 0, stream>>>(x, xt);
    k_qkv_flat<<<3600, 256, 0, stream>>>(wqb, b_qkv, xt, qTb, kTb, vBb);
    k_attn<<<B_ * H_, 256, 0, stream>>>(qTb, kTb, vBb, relb, aTb);
    k_out<<<768, 256, 0, stream>>>(wob, b_out, aTb, out);
}

// Round 9
// 193.807 us; speedup vs baseline: 1.1133x; 1.1133x over previous
//
#include <hip/hip_runtime.h>
#include <hip/hip_bf16.h>
#include <hip/hip_fp16.h>
#include <stdint.h>

// Problem dims (fixed): N=64, C=192, T=64, V=25, H=6, d=32, B=N*V=1600
#define N_ 64
#define C_ 192
#define T_ 64
#define V_ 25
#define H_ 6
#define D_ 32
#define B_ 1600
#define NQ_ (3 * C_ * C_)   // 110592
#define NO_ (C_ * C_)       // 36864

typedef __attribute__((ext_vector_type(8))) short s16x8;
typedef __attribute__((ext_vector_type(4))) short s16x4;
typedef __attribute__((ext_vector_type(4))) float f32x4;

__device__ __forceinline__ unsigned short f2bf(float f) {
    union { float f; uint32_t u; } v; v.f = f;
    uint32_t r = v.u + 0x7FFFu + ((v.u >> 16) & 1u);   // RNE
    return (unsigned short)(r >> 16);
}

// ---------------------------------------------------------------------------
// Kernel 1: merged  (a) x (N,C,T,V) fp32 -> xt[(n*V+v)][t][c] bf16  [768 blk]
//                   (b) weights+rel -> bf16                          [37 blk]
// xpose XCD-swizzled so each XCD produces b in [200*xcd, 200*(xcd+1)).
// ---------------------------------------------------------------------------
__global__ __launch_bounds__(256) void k_xw(const float* __restrict__ x,
                                            const float* __restrict__ wq,
                                            const float* __restrict__ wo,
                                            const float* __restrict__ rel_emb,
                                            unsigned short* __restrict__ xt,
                                            unsigned short* __restrict__ wqb,
                                            unsigned short* __restrict__ wob,
                                            unsigned short* __restrict__ relb) {
    int bid = blockIdx.x;
    if (bid >= 768) {
        int base = (bid - 768) * 4096 + threadIdx.x;
#pragma unroll
        for (int e = 0; e < 16; ++e) {
            int i = base + e * 256;
            if (i < NQ_) wqb[i] = f2bf(wq[i]);
            else if (i < NQ_ + NO_) wob[i - NQ_] = f2bf(wo[i - NQ_]);
            else {
                int j = i - (NQ_ + NO_);          // < 4096 by construction
                int m = j >> 5;
                relb[j] = (m < 127) ? f2bf(rel_emb[j]) : (unsigned short)0;
            }
        }
        return;
    }
    int virt = (bid & 7) * 96 + (bid >> 3);
    int n = virt / 12, r = virt % 12, cg = r >> 1, ih = r & 1;
    __shared__ unsigned short tile[800][40];   // 64000 B
    int tid = threadIdx.x;
    {
        int cc = tid >> 3, part = tid & 7;     // cc 0..31, 100 elems each
        const float4* src = (const float4*)(x + ((size_t)n * C_ + cg * 32 + cc) * 1600
                                              + ih * 800 + part * 100);
#pragma unroll
        for (int u = 0; u < 25; ++u) {
            float4 f = src[u];
            int i = part * 100 + u * 4;
            tile[i + 0][cc] = f2bf(f.x);
            tile[i + 1][cc] = f2bf(f.y);
            tile[i + 2][cc] = f2bf(f.z);
            tile[i + 3][cc] = f2bf(f.w);
        }
    }
    __syncthreads();
    for (int i = tid; i < 800; i += 256) {
        int gi = ih * 800 + i;
        int t = (gi * 5243) >> 17;             // gi/25 (exact for gi<1600)
        int v = gi - t * 25;
        unsigned short* dst = xt + (((size_t)(n * V_ + v) * T_) + t) * C_ + cg * 32;
        const s16x8* srow = (const s16x8*)&tile[i][0];
        ((s16x8*)dst)[0] = srow[0];
        ((s16x8*)dst)[1] = srow[1];
        ((s16x8*)dst)[2] = srow[2];
        ((s16x8*)dst)[3] = srow[3];
    }
}

// ---------------------------------------------------------------------------
// Kernel 2: QKV GEMM, round-5 structure (grid 14400, 64x64 tiles, 57% occ).
// Epilogue targets: mo 0..5 -> qT/kT[b][t][192] via col-major bounce with
// PACKED b64 LDS writes; mo 6..8 -> vB[b][d][t] via row-major bounce.
// ---------------------------------------------------------------------------
__global__ __launch_bounds__(256) void k_qkv(const unsigned short* __restrict__ Wb,
                                             const float* __restrict__ bias,
                                             const unsigned short* __restrict__ xt,
                                             unsigned short* __restrict__ qT,
                                             unsigned short* __restrict__ kT,
                                             unsigned short* __restrict__ vB) {
    int virt = (blockIdx.x & 7) * 1800 + (blockIdx.x >> 3);   // 14400 = 8*1800
    int b = virt / 9, mo = virt % 9;
    __shared__ unsigned short Bs[64][200];                 // xt tile, 25.6 KB
    __shared__ __align__(16) unsigned short Lb[64 * 68];   // bounce, 8.7 KB
    int tid = threadIdx.x;
    {
        int t = tid >> 2, q = tid & 3;
        const s16x8* src = (const s16x8*)(xt + ((size_t)b * T_ + t) * C_ + q * 48);
        s16x8* dst = (s16x8*)&Bs[t][q * 48];
        dst[0] = src[0]; dst[1] = src[1]; dst[2] = src[2];
        dst[3] = src[3]; dst[4] = src[4]; dst[5] = src[5];
    }
    __syncthreads();
    int wave = tid >> 6, lane = tid & 63;
    int lr = lane & 15, lg = lane >> 4;

    f32x4 acc[4];
#pragma unroll
    for (int nt = 0; nt < 4; ++nt) acc[nt] = (f32x4){0.f, 0.f, 0.f, 0.f};

    const unsigned short* arow = Wb + (size_t)(mo * 64 + wave * 16 + lr) * C_ + lg * 8;
#pragma unroll
    for (int k0 = 0; k0 < C_; k0 += 32) {
        s16x8 a = *(const s16x8*)(arow + k0);
#pragma unroll
        for (int nt = 0; nt < 4; ++nt) {
            s16x8 bf = *(const s16x8*)&Bs[nt * 16 + lr][k0 + lg * 8];
            acc[nt] = __builtin_amdgcn_mfma_f32_16x16x32_bf16(a, bf, acc[nt], 0, 0, 0);
        }
    }

    if (mo < 6) {
        // col-major bounce Lb[t][o'], packed 4-ushort (b64) writes
#pragma unroll
        for (int nt = 0; nt < 4; ++nt) {
            s16x4 pk;
#pragma unroll
            for (int r2 = 0; r2 < 4; ++r2)
                pk[r2] = (short)f2bf(acc[nt][r2] + bias[mo * 64 + wave * 16 + lg * 4 + r2]);
            *(s16x4*)&Lb[(nt * 16 + lr) * 68 + wave * 16 + lg * 4] = pk;
        }
        __syncthreads();
        unsigned short* dst0 = (mo < 3 ? qT : kT);
        int o0 = (mo % 3) * 64;
        for (int ci = tid; ci < 512; ci += 256) {
            int col = ci >> 3, seg = ci & 7;
            *(s16x8*)(dst0 + ((size_t)b * T_ + col) * C_ + o0 + seg * 8) =
                *(const s16x8*)&Lb[col * 68 + seg * 8];
        }
    } else {
        // row-major bounce Lb[o'][t]
#pragma unroll
        for (int nt = 0; nt < 4; ++nt)
#pragma unroll
            for (int r2 = 0; r2 < 4; ++r2) {
                int ol = wave * 16 + lg * 4 + r2;
                Lb[ol * 68 + nt * 16 + lr] = f2bf(acc[nt][r2] + bias[mo * 64 + ol]);
            }
        __syncthreads();
        int d0 = (mo - 6) * 64;
        for (int ci = tid; ci < 512; ci += 256) {
            int row = ci >> 3, seg = ci & 7;
            *(s16x8*)(vB + ((size_t)b * C_ + d0 + row) * T_ + seg * 8) =
                *(const s16x8*)&Lb[row * 68 + seg * 8];
        }
    }
}

// ---------------------------------------------------------------------------
// Kernel 3: fused attention per (b,h).  Windowed rel (5 m-tiles/wave, wave-
// private fp16 relw), rel B-frags direct from global relb (L2-hot), row-copy
// staging.  LDS 35.5 KB -> 4 blocks/CU.  13 MFMA/wave, 3 barriers.
// ---------------------------------------------------------------------------
__global__ __launch_bounds__(256) void k_attn(const unsigned short* __restrict__ qT,
                                              const unsigned short* __restrict__ kT,
                                              const unsigned short* __restrict__ vB,
                                              const unsigned short* __restrict__ relb,
                                              unsigned short* __restrict__ aT) {
    int virt = (blockIdx.x & 7) * (B_ * H_ / 8) + (blockIdx.x >> 3);
    int b = virt / H_, h = virt % H_;
    __shared__ unsigned short qt[64][40];      // [t][d]  5 KB
    __shared__ unsigned short kt[64][40];      // [s][d]  5 KB
    __shared__ unsigned short vsm[32][88];     // [d][t]  5.5 KB
    __shared__ unsigned short wls[64][72];     // weights [t][s] 9.2 KB
    __shared__ __half relw[4][16][88];         // wave-private windowed rel_l 11.3 KB
    unsigned short (*ao)[40] = (unsigned short(*)[40])&relw[0][0][0];  // 5 KB alias

    int tid = threadIdx.x;
    {
        int t = tid >> 2, sg = tid & 3;
        *(s16x8*)&qt[t][sg * 8] =
            *(const s16x8*)(qT + ((size_t)b * T_ + t) * C_ + h * D_ + sg * 8);
        *(s16x8*)&kt[t][sg * 8] =
            *(const s16x8*)(kT + ((size_t)b * T_ + t) * C_ + h * D_ + sg * 8);
    }
    {
        int d = tid >> 3, tg = tid & 7;
        *(s16x8*)&vsm[d][tg * 8] =
            *(const s16x8*)(vB + ((size_t)b * C_ + h * D_ + d) * T_ + tg * 8);
    }
    int wave = tid >> 6, lane = tid & 63;
    int lr = lane & 15, lg = lane >> 4;
    int t0 = wave * 16;
    int tA = t0 + lr;

    // rel fragments direct from global (identical 8KB for all blocks -> L2)
    s16x8 rfr[5];
#pragma unroll
    for (int ti = 0; ti < 5; ++ti) {
        int m = (3 - wave + ti) * 16 + lr;
        rfr[ti] = *(const s16x8*)(relb + m * 32 + lg * 8);
    }
    __syncthreads();

    s16x8 afq = *(const s16x8*)&qt[tA][lg * 8];

    // QK^T: 4 N-tiles over s
    f32x4 accS[4];
#pragma unroll
    for (int nt = 0; nt < 4; ++nt) {
        s16x8 bf = *(const s16x8*)&kt[nt * 16 + lr][lg * 8];
        f32x4 z = (f32x4){0.f, 0.f, 0.f, 0.f};
        accS[nt] = __builtin_amdgcn_mfma_f32_16x16x32_bf16(afq, bf, z, 0, 0, 0);
    }
    // windowed rel logits: 5 tiles, m = (3-wave+ti)*16+lr, col_local = ti*16+lr
#pragma unroll
    for (int ti = 0; ti < 5; ++ti) {
        f32x4 z = (f32x4){0.f, 0.f, 0.f, 0.f};
        f32x4 rr = __builtin_amdgcn_mfma_f32_16x16x32_bf16(afq, rfr[ti], z, 0, 0, 0);
#pragma unroll
        for (int r2 = 0; r2 < 4; ++r2)
            relw[wave][lg * 4 + r2][ti * 16 + lr] = __float2half(rr[r2]);
    }
    // NO barrier: relw is wave-private (reads below are same-wave)

    // softmax (fp32): lane owns rows (lg*4+r2), cols (nt*16+lr)
    float vals[4][4], mx[4], inv[4];
#pragma unroll
    for (int r2 = 0; r2 < 4; ++r2) {
        int row = lg * 4 + r2;
        float m0 = -1e30f;
#pragma unroll
        for (int nt = 0; nt < 4; ++nt) {
            int s = nt * 16 + lr;
            // global m = s-t+63 -> local col = s - row + 15  (in [0,78])
            float v = accS[nt][r2] + __half2float(relw[wave][row][s - row + 15]);
            vals[nt][r2] = v;
            m0 = fmaxf(m0, v);
        }
        m0 = fmaxf(m0, __shfl_xor(m0, 1));
        m0 = fmaxf(m0, __shfl_xor(m0, 2));
        m0 = fmaxf(m0, __shfl_xor(m0, 4));
        m0 = fmaxf(m0, __shfl_xor(m0, 8));
        mx[r2] = m0;
    }
#pragma unroll
    for (int r2 = 0; r2 < 4; ++r2) {
        float s0 = 0.f;
#pragma unroll
        for (int nt = 0; nt < 4; ++nt) {
            float e = __expf(vals[nt][r2] - mx[r2]);
            vals[nt][r2] = e;
            s0 += e;
        }
        s0 += __shfl_xor(s0, 1);
        s0 += __shfl_xor(s0, 2);
        s0 += __shfl_xor(s0, 4);
        s0 += __shfl_xor(s0, 8);
        inv[r2] = 1.0f / s0;
    }
#pragma unroll
    for (int r2 = 0; r2 < 4; ++r2) {
        int t = t0 + lg * 4 + r2;
#pragma unroll
        for (int nt = 0; nt < 4; ++nt)
            wls[t][nt * 16 + lr] = f2bf(vals[nt][r2] * inv[r2]);
    }
    __syncthreads();   // all relw reads done before ao overwrites; wls visible

    // PV: attn[t][dd] = sum_s w[t][s] * v[dd][s]
    f32x4 accO[2];
    accO[0] = (f32x4){0.f, 0.f, 0.f, 0.f};
    accO[1] = (f32x4){0.f, 0.f, 0.f, 0.f};
#pragma unroll
    for (int ks = 0; ks < 2; ++ks) {
        s16x8 pa = *(const s16x8*)&wls[tA][ks * 32 + lg * 8];
#pragma unroll
        for (int nt = 0; nt < 2; ++nt) {
            s16x8 bf = *(const s16x8*)&vsm[nt * 16 + lr][ks * 32 + lg * 8];
            accO[nt] = __builtin_amdgcn_mfma_f32_16x16x32_bf16(pa, bf, accO[nt], 0, 0, 0);
        }
    }
#pragma unroll
    for (int nt = 0; nt < 2; ++nt)
#pragma unroll
        for (int r2 = 0; r2 < 4; ++r2)
            ao[t0 + lg * 4 + r2][nt * 16 + lr] = f2bf(accO[nt][r2]);
    __syncthreads();

    // scrambled write: aT[b][tout][h*32+qr] = ao[tA][dA]
    unsigned short* dstb = aT + (size_t)b * T_ * C_ + h * D_;
#pragma unroll
    for (int it = 0; it < 8; ++it) {
        int idx = it * 256 + tid;
        int qr = idx & 31, tout = idx >> 5;
        int ii = tout & 31;
        int j = 2 * qr + (tout >> 5);
        int tAo = 2 * ii + (j >> 5);
        int dA = j & 31;
        dstb[(size_t)tout * C_ + qr] = ao[tAo][dA];
    }
}

// ---------------------------------------------------------------------------
// Kernel 4: out GEMM (bf16 MFMA), writes final (N,C,T,V) fp32. XCD-swizzled.
// ---------------------------------------------------------------------------
__global__ __launch_bounds__(256) void k_out(const unsigned short* __restrict__ Wb,
                                             const float* __restrict__ bias,
                                             const unsigned short* __restrict__ aT,
                                             float* __restrict__ out) {
    int virt = (blockIdx.x & 7) * (768 / 8) + (blockIdx.x >> 3);
    int n = virt / 12, r = virt % 12, mo = r >> 2, tc = r & 3;
    __shared__ unsigned short Bs[400][40];     // [col][k], 32KB
    int tid = threadIdx.x;
    int wave = tid >> 6, lane = tid & 63;
    int lr = lane & 15, lg = lane >> 4;

    f32x4 acc[25];
#pragma unroll
    for (int j = 0; j < 25; ++j) acc[j] = (f32x4){0.f, 0.f, 0.f, 0.f};

    const unsigned short* arow = Wb + (size_t)(mo * 64 + wave * 16 + lr) * C_ + lg * 8;

    for (int k0 = 0; k0 < C_; k0 += 32) {
        __syncthreads();
        for (int col = tid; col < 400; col += 256) {
            int tl = (col * 41) >> 10;         // col/25 (exact for col<624)
            int v = col - tl * 25;
            const s16x8* src = (const s16x8*)(aT +
                ((size_t)(n * V_ + v) * T_ + tc * 16 + tl) * C_ + k0);
            s16x8* dst = (s16x8*)&Bs[col][0];
            dst[0] = src[0]; dst[1] = src[1]; dst[2] = src[2]; dst[3] = src[3];
        }
        __syncthreads();
        s16x8 a = *(const s16x8*)(arow + k0);
#pragma unroll
        for (int j = 0; j < 25; ++j) {
            s16x8 bf = *(const s16x8*)&Bs[j * 16 + lr][lg * 8];
            acc[j] = __builtin_amdgcn_mfma_f32_16x16x32_bf16(a, bf, acc[j], 0, 0, 0);
        }
    }
#pragma unroll
    for (int j = 0; j < 25; ++j) {
        int c = j * 16 + lr;
        int tl = (c * 41) >> 10;
        int v = c - tl * 25;
        int t = tc * 16 + tl;
#pragma unroll
        for (int r2 = 0; r2 < 4; ++r2) {
            int o = mo * 64 + wave * 16 + lg * 4 + r2;
            out[(((size_t)n * C_ + o) * T_ + t) * V_ + v] = acc[j][r2] + bias[o];
        }
    }
}

// ---------------------------------------------------------------------------
extern "C" void kernel_launch(void* const* d_in, const int* in_sizes, int n_in,
                              void* d_out, int out_size, void* d_ws, size_t ws_size,
                              hipStream_t stream) {
    const float* x       = (const float*)d_in[0];
    const float* w_qkv   = (const float*)d_in[1];
    const float* b_qkv   = (const float*)d_in[2];
    const float* w_out   = (const float*)d_in[3];
    const float* b_out   = (const float*)d_in[4];
    const float* rel_emb = (const float*)d_in[5];
    float* out = (float*)d_out;

    // workspace (ushorts): xt | qT | kT | vB | aT | wqb | wob | relb (~197 MB)
    const size_t PLANE = (size_t)B_ * T_ * C_;   // 19,660,800
    unsigned short* xt   = (unsigned short*)d_ws;
    unsigned short* qTb  = xt + PLANE;
    unsigned short* kTb  = qTb + PLANE;
    unsigned short* vBb  = kTb + PLANE;
    unsigned short* aTb  = vBb + PLANE;
    unsigned short* wqb  = aTb + PLANE;
    unsigned short* wob  = wqb + (size_t)NQ_;
    unsigned short* relb = wob + (size_t)NO_;

    k_xw<<<805, 256, 0, stream>>>(x, w_qkv, w_out, rel_emb, xt, wqb, wob, relb);
    k_qkv<<<B_ * 9, 256, 0, stream>>>(wqb, b_qkv, xt, qTb, kTb, vBb);
    k_attn<<<B_ * H_, 256, 0, stream>>>(qTb, kTb, vBb, relb, aTb);
    k_out<<<768, 256, 0, stream>>>(wob, b_out, aTb, out);
}